// Round 1
// baseline (283.029 us; speedup 1.0000x reference)
//
#include <hip/hip_runtime.h>

#define H   256
#define H2  512
#define ROWS 16
#define LN_EPS 1e-5f

// ---------------- counting sort of node indices by group ----------------

__global__ void k_zero(int* __restrict__ counts, int G) {
    int i = blockIdx.x * blockDim.x + threadIdx.x;
    if (i < G) counts[i] = 0;
}

__global__ void k_hist(const int* __restrict__ fid, int* __restrict__ counts, int N) {
    int i = blockIdx.x * blockDim.x + threadIdx.x;
    int stride = gridDim.x * blockDim.x;
    for (; i < N; i += stride) atomicAdd(&counts[fid[i]], 1);
}

// single-block exclusive scan over G counters (G <= 1024*PER)
__global__ __launch_bounds__(1024) void k_scan(const int* __restrict__ counts,
                                               int* __restrict__ offsets,
                                               int* __restrict__ cursor, int G) {
    __shared__ int part[1024];
    const int t = threadIdx.x;
    const int per = (G + 1023) / 1024;           // 8 for G=8192
    const int base = t * per;
    int local[16];
    int s = 0;
    for (int j = 0; j < per; ++j) {
        int v = (base + j < G) ? counts[base + j] : 0;
        local[j] = s;                            // exclusive within thread
        s += v;
    }
    part[t] = s;
    __syncthreads();
    for (int off = 1; off < 1024; off <<= 1) {   // inclusive Hillis-Steele
        int v = 0;
        if (t >= off) v = part[t - off];
        __syncthreads();
        part[t] += v;
        __syncthreads();
    }
    int tbase = (t == 0) ? 0 : part[t - 1];
    for (int j = 0; j < per; ++j) {
        if (base + j < G) {
            int o = tbase + local[j];
            offsets[base + j] = o;
            cursor[base + j]  = o;
        }
    }
}

__global__ void k_scatter(const int* __restrict__ fid, int* __restrict__ cursor,
                          int* __restrict__ idx_sorted, int N) {
    int i = blockIdx.x * blockDim.x + threadIdx.x;
    int stride = gridDim.x * blockDim.x;
    for (; i < N; i += stride) {
        int g = fid[i];
        int pos = atomicAdd(&cursor[g], 1);
        idx_sorted[pos] = i;
    }
}

// ---------------- segment mean+max gather-reduce (1 wave / group) ----------------

__global__ __launch_bounds__(64) void k_reduce(const float* __restrict__ x,
                                               const int* __restrict__ idx,
                                               const int* __restrict__ offsets,
                                               const int* __restrict__ counts,
                                               float* __restrict__ pooled) {
    const int g = blockIdx.x;
    const int t = threadIdx.x;                   // 0..63, each owns 4 columns
    const int start = offsets[g];
    const int cnt   = counts[g];
    const float4* __restrict__ xv = (const float4*)x;   // row i -> xv[i*64 + t]

    float4 s = make_float4(0.f, 0.f, 0.f, 0.f);
    float ninf = -__builtin_inff();
    float4 m = make_float4(ninf, ninf, ninf, ninf);

    int j = 0;
    for (; j + 2 <= cnt; j += 2) {
        int i0 = idx[start + j];
        int i1 = idx[start + j + 1];
        float4 a = xv[(size_t)i0 * 64 + t];
        float4 b = xv[(size_t)i1 * 64 + t];
        s.x += a.x + b.x; s.y += a.y + b.y; s.z += a.z + b.z; s.w += a.w + b.w;
        m.x = fmaxf(m.x, fmaxf(a.x, b.x));
        m.y = fmaxf(m.y, fmaxf(a.y, b.y));
        m.z = fmaxf(m.z, fmaxf(a.z, b.z));
        m.w = fmaxf(m.w, fmaxf(a.w, b.w));
    }
    if (j < cnt) {
        int i0 = idx[start + j];
        float4 a = xv[(size_t)i0 * 64 + t];
        s.x += a.x; s.y += a.y; s.z += a.z; s.w += a.w;
        m.x = fmaxf(m.x, a.x); m.y = fmaxf(m.y, a.y);
        m.z = fmaxf(m.z, a.z); m.w = fmaxf(m.w, a.w);
    }
    float inv = 1.0f / (float)((cnt > 1) ? cnt : 1);
    float4 mean = make_float4(s.x * inv, s.y * inv, s.z * inv, s.w * inv);
    float4* pv = (float4*)pooled;
    pv[(size_t)g * 128 + t]      = mean;   // [g, 0:256]   mean
    pv[(size_t)g * 128 + 64 + t] = m;      // [g, 256:512] max
}

// ---------------- Wf_sum = Wf[0:256] + Wf[256:512] + Wf[512:768] ----------------

__global__ void k_wfsum(const float* __restrict__ Wf, float* __restrict__ Wfs) {
    int i = blockIdx.x * blockDim.x + threadIdx.x;
    if (i < H * H)
        Wfs[i] = Wf[i] + Wf[i + H * H] + Wf[i + 2 * H * H];
}

// ---------------- fused GEMM1+LN1+ReLU + GEMM2+LN2+ReLU ----------------

__global__ __launch_bounds__(256) void k_mlp(const float* __restrict__ pooled,
                                             const float* __restrict__ Wp,
                                             const float* __restrict__ bp,
                                             const float* __restrict__ g1,
                                             const float* __restrict__ b1,
                                             const float* __restrict__ Wfs,
                                             const float* __restrict__ bf,
                                             const float* __restrict__ g2,
                                             const float* __restrict__ b2,
                                             float* __restrict__ out, int G) {
    __shared__ float sp[ROWS][H2];          // 32 KB: pooled rows
    __shared__ float sf[ROWS][H];           // 16 KB: func rows
    __shared__ float red[4][ROWS][2];       // per-wave partials (sum, sumsq)

    const int g0 = blockIdx.x * ROWS;
    const int t  = threadIdx.x;             // output column 0..255
    const int lane = t & 63;
    const int wv   = t >> 6;

    // stage 16 pooled rows (contiguous 32 KB) into LDS, float4 vectorized
    {
        const float4* src = (const float4*)(pooled + (size_t)g0 * H2);
        float4* dst = (float4*)&sp[0][0];
        for (int j = t; j < ROWS * H2 / 4; j += 256) dst[j] = src[j];
    }
    __syncthreads();

    // ---- GEMM1: val[r] = pooled[g0+r,:] . Wp[:,t] + bp[t]
    float acc[ROWS];
    #pragma unroll
    for (int r = 0; r < ROWS; ++r) acc[r] = 0.f;

    for (int k = 0; k < H2; k += 4) {
        float w0 = Wp[(k + 0) * H + t];
        float w1 = Wp[(k + 1) * H + t];
        float w2 = Wp[(k + 2) * H + t];
        float w3 = Wp[(k + 3) * H + t];
        #pragma unroll
        for (int r = 0; r < ROWS; ++r) {
            float4 p = *(const float4*)&sp[r][k];
            acc[r] = fmaf(p.x, w0, acc[r]);
            acc[r] = fmaf(p.y, w1, acc[r]);
            acc[r] = fmaf(p.z, w2, acc[r]);
            acc[r] = fmaf(p.w, w3, acc[r]);
        }
    }
    {
        float bpv = bp[t];
        #pragma unroll
        for (int r = 0; r < ROWS; ++r) acc[r] += bpv;
    }

    // ---- LN1 reductions across the 256 columns (threads)
    #pragma unroll
    for (int r = 0; r < ROWS; ++r) {
        float s = acc[r], q = acc[r] * acc[r];
        #pragma unroll
        for (int off = 32; off; off >>= 1) {
            s += __shfl_xor(s, off, 64);
            q += __shfl_xor(q, off, 64);
        }
        if (lane == 0) { red[wv][r][0] = s; red[wv][r][1] = q; }
    }
    __syncthreads();
    {
        float g1v = g1[t], b1v = b1[t];
        #pragma unroll
        for (int r = 0; r < ROWS; ++r) {
            float s = red[0][r][0] + red[1][r][0] + red[2][r][0] + red[3][r][0];
            float q = red[0][r][1] + red[1][r][1] + red[2][r][1] + red[3][r][1];
            float mu = s * (1.0f / H);
            float var = q * (1.0f / H) - mu * mu;
            float v = (acc[r] - mu) * rsqrtf(var + LN_EPS) * g1v + b1v;
            sf[r][t] = fmaxf(v, 0.f);       // ReLU -> func
        }
    }
    __syncthreads();

    // ---- GEMM2: val[r] = func[g0+r,:] . Wfs[:,t] + bf[t]
    float acc2[ROWS];
    #pragma unroll
    for (int r = 0; r < ROWS; ++r) acc2[r] = 0.f;

    for (int k = 0; k < H; k += 4) {
        float w0 = Wfs[(k + 0) * H + t];
        float w1 = Wfs[(k + 1) * H + t];
        float w2 = Wfs[(k + 2) * H + t];
        float w3 = Wfs[(k + 3) * H + t];
        #pragma unroll
        for (int r = 0; r < ROWS; ++r) {
            float4 p = *(const float4*)&sf[r][k];
            acc2[r] = fmaf(p.x, w0, acc2[r]);
            acc2[r] = fmaf(p.y, w1, acc2[r]);
            acc2[r] = fmaf(p.z, w2, acc2[r]);
            acc2[r] = fmaf(p.w, w3, acc2[r]);
        }
    }
    {
        float bfv = bf[t];
        #pragma unroll
        for (int r = 0; r < ROWS; ++r) acc2[r] += bfv;
    }
    __syncthreads();     // red reuse safe (all reads done pre-sf barrier, but be explicit)

    // ---- LN2
    #pragma unroll
    for (int r = 0; r < ROWS; ++r) {
        float s = acc2[r], q = acc2[r] * acc2[r];
        #pragma unroll
        for (int off = 32; off; off >>= 1) {
            s += __shfl_xor(s, off, 64);
            q += __shfl_xor(q, off, 64);
        }
        if (lane == 0) { red[wv][r][0] = s; red[wv][r][1] = q; }
    }
    __syncthreads();
    {
        float g2v = g2[t], b2v = b2[t];
        #pragma unroll
        for (int r = 0; r < ROWS; ++r) {
            float s = red[0][r][0] + red[1][r][0] + red[2][r][0] + red[3][r][0];
            float q = red[0][r][1] + red[1][r][1] + red[2][r][1] + red[3][r][1];
            float mu = s * (1.0f / H);
            float var = q * (1.0f / H) - mu * mu;
            float v = (acc2[r] - mu) * rsqrtf(var + LN_EPS) * g2v + b2v;
            int g = g0 + r;
            if (g < G) out[(size_t)g * H + t] = fmaxf(v, 0.f);
        }
    }
}

// ---------------- launch ----------------

extern "C" void kernel_launch(void* const* d_in, const int* in_sizes, int n_in,
                              void* d_out, int out_size, void* d_ws, size_t ws_size,
                              hipStream_t stream) {
    const float* x   = (const float*)d_in[0];
    const int*   fid = (const int*)d_in[2];
    const float* Wp  = (const float*)d_in[3];
    const float* bp  = (const float*)d_in[4];
    const float* g1  = (const float*)d_in[5];
    const float* b1  = (const float*)d_in[6];
    const float* Wf  = (const float*)d_in[7];
    const float* bf  = (const float*)d_in[8];
    const float* g2  = (const float*)d_in[9];
    const float* b2  = (const float*)d_in[10];
    float* out = (float*)d_out;

    const int N = in_sizes[1];              // 500000
    const int G = out_size / H;             // 8192

    char* w = (char*)d_ws;
    int* counts  = (int*)w;  w += (size_t)G * sizeof(int);
    int* offsets = (int*)w;  w += (size_t)G * sizeof(int);
    int* cursor  = (int*)w;  w += (size_t)G * sizeof(int);
    int* idx     = (int*)w;  w += (size_t)N * sizeof(int);
    // keep 16B alignment for pooled
    w = (char*)(((uintptr_t)w + 15) & ~(uintptr_t)15);
    float* pooled = (float*)w; w += (size_t)G * H2 * sizeof(float);
    float* Wfs    = (float*)w; w += (size_t)H * H * sizeof(float);

    hipLaunchKernelGGL(k_zero,   dim3((G + 255) / 256), dim3(256), 0, stream, counts, G);
    hipLaunchKernelGGL(k_hist,   dim3(1024), dim3(256), 0, stream, fid, counts, N);
    hipLaunchKernelGGL(k_scan,   dim3(1), dim3(1024), 0, stream, counts, offsets, cursor, G);
    hipLaunchKernelGGL(k_scatter,dim3(1024), dim3(256), 0, stream, fid, cursor, idx, N);
    hipLaunchKernelGGL(k_wfsum,  dim3((H * H + 255) / 256), dim3(256), 0, stream, Wf, Wfs);
    hipLaunchKernelGGL(k_reduce, dim3(G), dim3(64), 0, stream, x, idx, offsets, counts, pooled);
    hipLaunchKernelGGL(k_mlp,    dim3((G + ROWS - 1) / ROWS), dim3(256), 0, stream,
                       pooled, Wp, bp, g1, b1, Wfs, bf, g2, b2, out, G);
}

// Round 2
// 214.981 us; speedup vs baseline: 1.3165x; 1.3165x over previous
//
#include <hip/hip_runtime.h>

#define H   256
#define H2  512
#define ROWS 16
#define KT  32
#define LN_EPS 1e-5f

// ---------------- counting sort of node indices by group ----------------

__global__ void k_zero(int* __restrict__ counts, int G) {
    int i = blockIdx.x * blockDim.x + threadIdx.x;
    if (i < G) counts[i] = 0;
}

// histogram + per-node rank (old value of the atomic)
__global__ void k_hist_rank(const int* __restrict__ fid, int* __restrict__ counts,
                            int* __restrict__ rank, int N) {
    int i = blockIdx.x * blockDim.x + threadIdx.x;
    int stride = gridDim.x * blockDim.x;
    for (; i < N; i += stride) rank[i] = atomicAdd(&counts[fid[i]], 1);
}

// single-block exclusive scan over G counters
__global__ __launch_bounds__(1024) void k_scan(const int* __restrict__ counts,
                                               int* __restrict__ offsets, int G) {
    __shared__ int part[1024];
    const int t = threadIdx.x;
    const int per = (G + 1023) / 1024;           // 8 for G=8192
    const int base = t * per;
    int local[16];
    int s = 0;
    for (int j = 0; j < per; ++j) {
        int v = (base + j < G) ? counts[base + j] : 0;
        local[j] = s;
        s += v;
    }
    part[t] = s;
    __syncthreads();
    for (int off = 1; off < 1024; off <<= 1) {
        int v = 0;
        if (t >= off) v = part[t - off];
        __syncthreads();
        part[t] += v;
        __syncthreads();
    }
    int tbase = (t == 0) ? 0 : part[t - 1];
    for (int j = 0; j < per; ++j)
        if (base + j < G) offsets[base + j] = tbase + local[j];
}

// atomic-free scatter using precomputed rank
__global__ void k_scatter(const int* __restrict__ fid, const int* __restrict__ rank,
                          const int* __restrict__ offsets,
                          int* __restrict__ idx_sorted, int N) {
    int i = blockIdx.x * blockDim.x + threadIdx.x;
    int stride = gridDim.x * blockDim.x;
    for (; i < N; i += stride)
        idx_sorted[offsets[fid[i]] + rank[i]] = i;
}

// ---------------- segment mean+max gather-reduce (1 wave / group) ----------------

__global__ __launch_bounds__(64) void k_reduce(const float* __restrict__ x,
                                               const int* __restrict__ idx,
                                               const int* __restrict__ offsets,
                                               const int* __restrict__ counts,
                                               float* __restrict__ pooled) {
    const int g = blockIdx.x;
    const int t = threadIdx.x;                   // 0..63, each owns 4 columns
    const int start = offsets[g];
    const int cnt   = counts[g];
    const float4* __restrict__ xv = (const float4*)x;

    float4 s = make_float4(0.f, 0.f, 0.f, 0.f);
    const float ninf = -__builtin_inff();
    float4 m = make_float4(ninf, ninf, ninf, ninf);

    int j = 0;
    for (; j + 4 <= cnt; j += 4) {               // 4 outstanding 1KB loads / wave
        int i0 = idx[start + j + 0];
        int i1 = idx[start + j + 1];
        int i2 = idx[start + j + 2];
        int i3 = idx[start + j + 3];
        float4 a = xv[(size_t)i0 * 64 + t];
        float4 b = xv[(size_t)i1 * 64 + t];
        float4 c = xv[(size_t)i2 * 64 + t];
        float4 d = xv[(size_t)i3 * 64 + t];
        s.x += (a.x + b.x) + (c.x + d.x);
        s.y += (a.y + b.y) + (c.y + d.y);
        s.z += (a.z + b.z) + (c.z + d.z);
        s.w += (a.w + b.w) + (c.w + d.w);
        m.x = fmaxf(m.x, fmaxf(fmaxf(a.x, b.x), fmaxf(c.x, d.x)));
        m.y = fmaxf(m.y, fmaxf(fmaxf(a.y, b.y), fmaxf(c.y, d.y)));
        m.z = fmaxf(m.z, fmaxf(fmaxf(a.z, b.z), fmaxf(c.z, d.z)));
        m.w = fmaxf(m.w, fmaxf(fmaxf(a.w, b.w), fmaxf(c.w, d.w)));
    }
    for (; j < cnt; ++j) {
        int i0 = idx[start + j];
        float4 a = xv[(size_t)i0 * 64 + t];
        s.x += a.x; s.y += a.y; s.z += a.z; s.w += a.w;
        m.x = fmaxf(m.x, a.x); m.y = fmaxf(m.y, a.y);
        m.z = fmaxf(m.z, a.z); m.w = fmaxf(m.w, a.w);
    }
    float inv = 1.0f / (float)((cnt > 1) ? cnt : 1);
    float4 mean = make_float4(s.x * inv, s.y * inv, s.z * inv, s.w * inv);
    float4* pv = (float4*)pooled;
    pv[(size_t)g * 128 + t]      = mean;
    pv[(size_t)g * 128 + 64 + t] = m;
}

// ---------------- Wf_sum ----------------

__global__ void k_wfsum(const float* __restrict__ Wf, float* __restrict__ Wfs) {
    int i = blockIdx.x * blockDim.x + threadIdx.x;
    if (i < H * H)
        Wfs[i] = Wf[i] + Wf[i + H * H] + Wf[i + 2 * H * H];
}

// ---------------- fused MLP: register-tiled 4x4 per thread ----------------
// block: 256 threads = 4 waves. wave rg owns rows rg*4..rg*4+3 (uniform per wave
// -> A-reads are LDS broadcasts). lane cq owns cols cq*4..cq*4+3 (b128, conflict-free).

__global__ __launch_bounds__(256) void k_mlp(const float* __restrict__ pooled,
                                             const float* __restrict__ Wp,
                                             const float* __restrict__ bp,
                                             const float* __restrict__ g1,
                                             const float* __restrict__ b1,
                                             const float* __restrict__ Wfs,
                                             const float* __restrict__ bf,
                                             const float* __restrict__ g2,
                                             const float* __restrict__ b2,
                                             float* __restrict__ out, int G) {
    __shared__ float sp[ROWS][H2];          // 32 KB pooled rows
    __shared__ float sW[KT][H];             // 32 KB weight tile
    __shared__ float sf[ROWS][H];           // 16 KB func rows

    const int t  = threadIdx.x;
    const int cq = t & 63;
    const int rg = t >> 6;                  // wave id == row group
    const int c0 = cq * 4;
    const int r0 = rg * 4;
    const int g0 = blockIdx.x * ROWS;

    // stage pooled rows (contiguous 32 KB)
    {
        const float4* src = (const float4*)(pooled + (size_t)g0 * H2);
        float4* dst = (float4*)&sp[0][0];
        #pragma unroll
        for (int j = 0; j < 8; ++j) dst[t + j * 256] = src[t + j * 256];
    }
    __syncthreads();

    // ---- GEMM1: acc[rr][i] = pooled[g0+r0+rr,:] . Wp[:, c0+i]
    float acc[4][4];
    #pragma unroll
    for (int rr = 0; rr < 4; ++rr)
        #pragma unroll
        for (int i = 0; i < 4; ++i) acc[rr][i] = 0.f;

    for (int k0 = 0; k0 < H2; k0 += KT) {
        {   // stage Wp tile [KT][H]
            const float4* src = (const float4*)(Wp + (size_t)k0 * H);
            float4* dst = (float4*)&sW[0][0];
            #pragma unroll
            for (int j = 0; j < KT * H / 4 / 256; ++j)
                dst[t + j * 256] = src[t + j * 256];
        }
        __syncthreads();
        #pragma unroll 8
        for (int kk = 0; kk < KT; ++kk) {
            float4 b = *(const float4*)&sW[kk][c0];
            float a0 = sp[r0 + 0][k0 + kk];
            float a1 = sp[r0 + 1][k0 + kk];
            float a2 = sp[r0 + 2][k0 + kk];
            float a3 = sp[r0 + 3][k0 + kk];
            acc[0][0] = fmaf(a0, b.x, acc[0][0]);
            acc[0][1] = fmaf(a0, b.y, acc[0][1]);
            acc[0][2] = fmaf(a0, b.z, acc[0][2]);
            acc[0][3] = fmaf(a0, b.w, acc[0][3]);
            acc[1][0] = fmaf(a1, b.x, acc[1][0]);
            acc[1][1] = fmaf(a1, b.y, acc[1][1]);
            acc[1][2] = fmaf(a1, b.z, acc[1][2]);
            acc[1][3] = fmaf(a1, b.w, acc[1][3]);
            acc[2][0] = fmaf(a2, b.x, acc[2][0]);
            acc[2][1] = fmaf(a2, b.y, acc[2][1]);
            acc[2][2] = fmaf(a2, b.z, acc[2][2]);
            acc[2][3] = fmaf(a2, b.w, acc[2][3]);
            acc[3][0] = fmaf(a3, b.x, acc[3][0]);
            acc[3][1] = fmaf(a3, b.y, acc[3][1]);
            acc[3][2] = fmaf(a3, b.z, acc[3][2]);
            acc[3][3] = fmaf(a3, b.w, acc[3][3]);
        }
        __syncthreads();
    }

    // ---- bias + LN1 + ReLU -> sf (wave-local rows)
    {
        float4 bpv = *(const float4*)&bp[c0];
        float4 g1v = *(const float4*)&g1[c0];
        float4 b1v = *(const float4*)&b1[c0];
        #pragma unroll
        for (int rr = 0; rr < 4; ++rr) {
            float v0 = acc[rr][0] + bpv.x;
            float v1 = acc[rr][1] + bpv.y;
            float v2 = acc[rr][2] + bpv.z;
            float v3 = acc[rr][3] + bpv.w;
            float s = (v0 + v1) + (v2 + v3);
            float q = v0 * v0 + v1 * v1 + v2 * v2 + v3 * v3;
            #pragma unroll
            for (int off = 32; off; off >>= 1) {
                s += __shfl_xor(s, off, 64);
                q += __shfl_xor(q, off, 64);
            }
            float mu  = s * (1.0f / H);
            float var = q * (1.0f / H) - mu * mu;
            float rs  = rsqrtf(var + LN_EPS);
            float4 o;
            o.x = fmaxf((v0 - mu) * rs * g1v.x + b1v.x, 0.f);
            o.y = fmaxf((v1 - mu) * rs * g1v.y + b1v.y, 0.f);
            o.z = fmaxf((v2 - mu) * rs * g1v.z + b1v.z, 0.f);
            o.w = fmaxf((v3 - mu) * rs * g1v.w + b1v.w, 0.f);
            *(float4*)&sf[r0 + rr][c0] = o;   // wave-local: only this wave reads it
        }
    }

    // ---- GEMM2: acc2 = func . Wfs[:, c]
    float acc2[4][4];
    #pragma unroll
    for (int rr = 0; rr < 4; ++rr)
        #pragma unroll
        for (int i = 0; i < 4; ++i) acc2[rr][i] = 0.f;

    for (int k0 = 0; k0 < H; k0 += KT) {
        {   // stage Wfs tile
            const float4* src = (const float4*)(Wfs + (size_t)k0 * H);
            float4* dst = (float4*)&sW[0][0];
            #pragma unroll
            for (int j = 0; j < KT * H / 4 / 256; ++j)
                dst[t + j * 256] = src[t + j * 256];
        }
        __syncthreads();
        #pragma unroll 8
        for (int kk = 0; kk < KT; ++kk) {
            float4 b = *(const float4*)&sW[kk][c0];
            float a0 = sf[r0 + 0][k0 + kk];
            float a1 = sf[r0 + 1][k0 + kk];
            float a2 = sf[r0 + 2][k0 + kk];
            float a3 = sf[r0 + 3][k0 + kk];
            acc2[0][0] = fmaf(a0, b.x, acc2[0][0]);
            acc2[0][1] = fmaf(a0, b.y, acc2[0][1]);
            acc2[0][2] = fmaf(a0, b.z, acc2[0][2]);
            acc2[0][3] = fmaf(a0, b.w, acc2[0][3]);
            acc2[1][0] = fmaf(a1, b.x, acc2[1][0]);
            acc2[1][1] = fmaf(a1, b.y, acc2[1][1]);
            acc2[1][2] = fmaf(a1, b.z, acc2[1][2]);
            acc2[1][3] = fmaf(a1, b.w, acc2[1][3]);
            acc2[2][0] = fmaf(a2, b.x, acc2[2][0]);
            acc2[2][1] = fmaf(a2, b.y, acc2[2][1]);
            acc2[2][2] = fmaf(a2, b.z, acc2[2][2]);
            acc2[2][3] = fmaf(a2, b.w, acc2[2][3]);
            acc2[3][0] = fmaf(a3, b.x, acc2[3][0]);
            acc2[3][1] = fmaf(a3, b.y, acc2[3][1]);
            acc2[3][2] = fmaf(a3, b.z, acc2[3][2]);
            acc2[3][3] = fmaf(a3, b.w, acc2[3][3]);
        }
        __syncthreads();
    }

    // ---- bias + LN2 + ReLU -> out
    {
        float4 bfv = *(const float4*)&bf[c0];
        float4 g2v = *(const float4*)&g2[c0];
        float4 b2v = *(const float4*)&b2[c0];
        #pragma unroll
        for (int rr = 0; rr < 4; ++rr) {
            float v0 = acc2[rr][0] + bfv.x;
            float v1 = acc2[rr][1] + bfv.y;
            float v2 = acc2[rr][2] + bfv.z;
            float v3 = acc2[rr][3] + bfv.w;
            float s = (v0 + v1) + (v2 + v3);
            float q = v0 * v0 + v1 * v1 + v2 * v2 + v3 * v3;
            #pragma unroll
            for (int off = 32; off; off >>= 1) {
                s += __shfl_xor(s, off, 64);
                q += __shfl_xor(q, off, 64);
            }
            float mu  = s * (1.0f / H);
            float var = q * (1.0f / H) - mu * mu;
            float rs  = rsqrtf(var + LN_EPS);
            float4 o;
            o.x = fmaxf((v0 - mu) * rs * g2v.x + b2v.x, 0.f);
            o.y = fmaxf((v1 - mu) * rs * g2v.y + b2v.y, 0.f);
            o.z = fmaxf((v2 - mu) * rs * g2v.z + b2v.z, 0.f);
            o.w = fmaxf((v3 - mu) * rs * g2v.w + b2v.w, 0.f);
            int g = g0 + r0 + rr;
            if (g < G) *(float4*)&out[(size_t)g * H + c0] = o;
        }
    }
}

// ---------------- launch ----------------

extern "C" void kernel_launch(void* const* d_in, const int* in_sizes, int n_in,
                              void* d_out, int out_size, void* d_ws, size_t ws_size,
                              hipStream_t stream) {
    const float* x   = (const float*)d_in[0];
    const int*   fid = (const int*)d_in[2];
    const float* Wp  = (const float*)d_in[3];
    const float* bp  = (const float*)d_in[4];
    const float* g1  = (const float*)d_in[5];
    const float* b1  = (const float*)d_in[6];
    const float* Wf  = (const float*)d_in[7];
    const float* bf  = (const float*)d_in[8];
    const float* g2  = (const float*)d_in[9];
    const float* b2  = (const float*)d_in[10];
    float* out = (float*)d_out;

    const int N = in_sizes[1];              // 500000
    const int G = out_size / H;             // 8192

    char* w = (char*)d_ws;
    int* counts  = (int*)w;  w += (size_t)G * sizeof(int);
    int* offsets = (int*)w;  w += (size_t)G * sizeof(int);
    int* rank    = (int*)w;  w += (size_t)N * sizeof(int);
    int* idx     = (int*)w;  w += (size_t)N * sizeof(int);
    w = (char*)(((uintptr_t)w + 15) & ~(uintptr_t)15);
    float* pooled = (float*)w; w += (size_t)G * H2 * sizeof(float);
    float* Wfs    = (float*)w; w += (size_t)H * H * sizeof(float);

    hipLaunchKernelGGL(k_zero,      dim3((G + 255) / 256), dim3(256), 0, stream, counts, G);
    hipLaunchKernelGGL(k_hist_rank, dim3(1024), dim3(256), 0, stream, fid, counts, rank, N);
    hipLaunchKernelGGL(k_scan,      dim3(1), dim3(1024), 0, stream, counts, offsets, G);
    hipLaunchKernelGGL(k_scatter,   dim3(1024), dim3(256), 0, stream, fid, rank, offsets, idx, N);
    hipLaunchKernelGGL(k_wfsum,     dim3((H * H + 255) / 256), dim3(256), 0, stream, Wf, Wfs);
    hipLaunchKernelGGL(k_reduce,    dim3(G), dim3(64), 0, stream, x, idx, offsets, counts, pooled);
    hipLaunchKernelGGL(k_mlp,       dim3((G + ROWS - 1) / ROWS), dim3(256), 0, stream,
                       pooled, Wp, bp, g1, b1, Wfs, bf, g2, b2, out, G);
}

// Round 3
// 190.721 us; speedup vs baseline: 1.4840x; 1.1272x over previous
//
#include <hip/hip_runtime.h>

#define H   256
#define H2  512
#define ROWS 16
#define KT  32
#define LN_EPS 1e-5f

typedef _Float16 half4v __attribute__((ext_vector_type(4)));
typedef float    f32x4  __attribute__((ext_vector_type(4)));

#define SP_STRIDE 520   // 512 + 8 f16 pad (breaks bank conflicts on A b64 reads)
#define SF_STRIDE 264   // 256 + 8

// ---------------- counting sort of node indices by group ----------------

__global__ void k_zero(int* __restrict__ counts, int G) {
    int i = blockIdx.x * blockDim.x + threadIdx.x;
    if (i < G) counts[i] = 0;
}

__global__ void k_hist_rank(const int* __restrict__ fid, int* __restrict__ counts,
                            int* __restrict__ rank, int N) {
    int i = blockIdx.x * blockDim.x + threadIdx.x;
    int stride = gridDim.x * blockDim.x;
    for (; i < N; i += stride) rank[i] = atomicAdd(&counts[fid[i]], 1);
}

__global__ __launch_bounds__(1024) void k_scan(const int* __restrict__ counts,
                                               int* __restrict__ offsets, int G) {
    __shared__ int part[1024];
    const int t = threadIdx.x;
    const int per = (G + 1023) / 1024;
    const int base = t * per;
    int local[16];
    int s = 0;
    for (int j = 0; j < per; ++j) {
        int v = (base + j < G) ? counts[base + j] : 0;
        local[j] = s;
        s += v;
    }
    part[t] = s;
    __syncthreads();
    for (int off = 1; off < 1024; off <<= 1) {
        int v = 0;
        if (t >= off) v = part[t - off];
        __syncthreads();
        part[t] += v;
        __syncthreads();
    }
    int tbase = (t == 0) ? 0 : part[t - 1];
    for (int j = 0; j < per; ++j)
        if (base + j < G) offsets[base + j] = tbase + local[j];
}

__global__ void k_scatter(const int* __restrict__ fid, const int* __restrict__ rank,
                          const int* __restrict__ offsets,
                          int* __restrict__ idx_sorted, int N) {
    int i = blockIdx.x * blockDim.x + threadIdx.x;
    int stride = gridDim.x * blockDim.x;
    for (; i < N; i += stride)
        idx_sorted[offsets[fid[i]] + rank[i]] = i;
}

// ---------------- weight prep: f16 casts + Wf fold ----------------

__global__ void k_prep(const float* __restrict__ Wp, const float* __restrict__ Wf,
                       _Float16* __restrict__ WpH, _Float16* __restrict__ WfsH) {
    int i = blockIdx.x * blockDim.x + threadIdx.x;
    int stride = gridDim.x * blockDim.x;
    for (int j = i; j < H2 * H; j += stride) WpH[j] = (_Float16)Wp[j];
    for (int j = i; j < H * H; j += stride)
        WfsH[j] = (_Float16)(Wf[j] + Wf[j + H * H] + Wf[j + 2 * H * H]);
}

// ---------------- segment mean+max gather-reduce (4 waves / block) ----------------

__global__ __launch_bounds__(256) void k_reduce(const float* __restrict__ x,
                                                const int* __restrict__ idx,
                                                const int* __restrict__ offsets,
                                                const int* __restrict__ counts,
                                                float* __restrict__ pooled, int G) {
    const int g = blockIdx.x * 4 + (threadIdx.x >> 6);
    if (g >= G) return;
    const int t = threadIdx.x & 63;
    const int start = offsets[g];
    const int cnt   = counts[g];
    const float4* __restrict__ xv = (const float4*)x;

    float4 s = make_float4(0.f, 0.f, 0.f, 0.f);
    const float ninf = -__builtin_inff();
    float4 m = make_float4(ninf, ninf, ninf, ninf);

    int j = 0;
    for (; j + 4 <= cnt; j += 4) {
        int i0 = idx[start + j + 0];
        int i1 = idx[start + j + 1];
        int i2 = idx[start + j + 2];
        int i3 = idx[start + j + 3];
        float4 a = xv[(size_t)i0 * 64 + t];
        float4 b = xv[(size_t)i1 * 64 + t];
        float4 c = xv[(size_t)i2 * 64 + t];
        float4 d = xv[(size_t)i3 * 64 + t];
        s.x += (a.x + b.x) + (c.x + d.x);
        s.y += (a.y + b.y) + (c.y + d.y);
        s.z += (a.z + b.z) + (c.z + d.z);
        s.w += (a.w + b.w) + (c.w + d.w);
        m.x = fmaxf(m.x, fmaxf(fmaxf(a.x, b.x), fmaxf(c.x, d.x)));
        m.y = fmaxf(m.y, fmaxf(fmaxf(a.y, b.y), fmaxf(c.y, d.y)));
        m.z = fmaxf(m.z, fmaxf(fmaxf(a.z, b.z), fmaxf(c.z, d.z)));
        m.w = fmaxf(m.w, fmaxf(fmaxf(a.w, b.w), fmaxf(c.w, d.w)));
    }
    for (; j < cnt; ++j) {
        int i0 = idx[start + j];
        float4 a = xv[(size_t)i0 * 64 + t];
        s.x += a.x; s.y += a.y; s.z += a.z; s.w += a.w;
        m.x = fmaxf(m.x, a.x); m.y = fmaxf(m.y, a.y);
        m.z = fmaxf(m.z, a.z); m.w = fmaxf(m.w, a.w);
    }
    float inv = 1.0f / (float)((cnt > 1) ? cnt : 1);
    float4 mean = make_float4(s.x * inv, s.y * inv, s.z * inv, s.w * inv);
    float4* pv = (float4*)pooled;
    pv[(size_t)g * 128 + t]      = mean;
    pv[(size_t)g * 128 + 64 + t] = m;
}

// ---------------- fused MLP via MFMA f16 (16x16x16, fp32 accum) ----------------
// block: 256 thr = 4 waves. 16 group-rows per block, 256 out cols.
// wave w owns cols [64w, 64w+64) as 4 16x16 fragments. K-loop over LDS tiles.
// Fragment layouts (v_mfma_f32_16x16x16_f16):
//   A: lane l holds A[l&15][4*(l>>4)+j]      (half4 contiguous in k)
//   B: lane l holds B[4*(l>>4)+j][l&15]      (4 strided u16 reads)
//   D: lane l reg r -> row 4*(l>>4)+r, col l&15

__global__ __launch_bounds__(256) void k_mlp(const float* __restrict__ pooled,
                                             const _Float16* __restrict__ WpH,
                                             const float* __restrict__ bp,
                                             const float* __restrict__ g1,
                                             const float* __restrict__ b1,
                                             const _Float16* __restrict__ WfsH,
                                             const float* __restrict__ bf,
                                             const float* __restrict__ g2,
                                             const float* __restrict__ b2,
                                             float* __restrict__ out, int G) {
    __shared__ _Float16 spH[ROWS][SP_STRIDE];   // ~16.3 KB pooled rows (f16)
    __shared__ _Float16 sW[KT][H];              // 16 KB weight tile
    __shared__ _Float16 sfH[ROWS][SF_STRIDE];   // ~8.3 KB func rows (f16)
    __shared__ float red[4][ROWS][2];

    const int t   = threadIdx.x;
    const int l   = t & 63;
    const int w   = t >> 6;
    const int li  = l & 15;
    const int grp = l >> 4;                     // 0..3
    const int cb  = w * 64;
    const int g0  = blockIdx.x * ROWS;

    // ---- stage pooled rows -> f16 LDS (padded stride)
    {
        const float4* src = (const float4*)(pooled + (size_t)g0 * H2);
        for (int j = t; j < ROWS * H2 / 4; j += 256) {
            float4 v = src[j];
            int r = j >> 7;                     // (j*4)/512
            int k = (j << 2) & (H2 - 1);
            _Float16* d = &spH[r][k];
            d[0] = (_Float16)v.x; d[1] = (_Float16)v.y;
            d[2] = (_Float16)v.z; d[3] = (_Float16)v.w;
        }
    }
    __syncthreads();

    // per-thread output columns (4 fragments)
    int col[4];
    #pragma unroll
    for (int f = 0; f < 4; ++f) col[f] = cb + f * 16 + li;

    // ---- GEMM1: K = 512
    f32x4 acc[4];
    #pragma unroll
    for (int f = 0; f < 4; ++f) acc[f] = (f32x4)(0.f);

    for (int k0 = 0; k0 < H2; k0 += KT) {
        {   // stage WpH tile [KT][H] (contiguous 16 KB)
            const int4* src = (const int4*)(WpH + (size_t)k0 * H);
            int4* dst = (int4*)&sW[0][0];
            #pragma unroll
            for (int j = 0; j < 4; ++j) dst[t + j * 256] = src[t + j * 256];
        }
        __syncthreads();
        #pragma unroll
        for (int ks = 0; ks < 2; ++ks) {
            const int kb = ks * 16 + 4 * grp;
            half4v a = *(const half4v*)&spH[li][k0 + kb];
            #pragma unroll
            for (int f = 0; f < 4; ++f) {
                half4v b;
                b[0] = sW[kb + 0][col[f]];
                b[1] = sW[kb + 1][col[f]];
                b[2] = sW[kb + 2][col[f]];
                b[3] = sW[kb + 3][col[f]];
                acc[f] = __builtin_amdgcn_mfma_f32_16x16x16f16(a, b, acc[f], 0, 0, 0);
            }
        }
        __syncthreads();
    }

    // ---- bias + LN1 + ReLU -> sfH
    {
        float bpv[4], g1v[4], b1v[4];
        #pragma unroll
        for (int f = 0; f < 4; ++f) { bpv[f] = bp[col[f]]; g1v[f] = g1[col[f]]; b1v[f] = b1[col[f]]; }

        float vv[4][4], sum[4] = {0,0,0,0}, sq[4] = {0,0,0,0};
        #pragma unroll
        for (int f = 0; f < 4; ++f)
            #pragma unroll
            for (int r = 0; r < 4; ++r) {
                float v = acc[f][r] + bpv[f];
                vv[f][r] = v;
                sum[r] += v; sq[r] += v * v;
            }
        #pragma unroll
        for (int r = 0; r < 4; ++r) {
            #pragma unroll
            for (int off = 1; off < 16; off <<= 1) {
                sum[r] += __shfl_xor(sum[r], off, 64);
                sq[r]  += __shfl_xor(sq[r],  off, 64);
            }
        }
        if (li == 0) {
            #pragma unroll
            for (int r = 0; r < 4; ++r) {
                red[w][4 * grp + r][0] = sum[r];
                red[w][4 * grp + r][1] = sq[r];
            }
        }
        __syncthreads();
        #pragma unroll
        for (int r = 0; r < 4; ++r) {
            int R = 4 * grp + r;
            float s = red[0][R][0] + red[1][R][0] + red[2][R][0] + red[3][R][0];
            float q = red[0][R][1] + red[1][R][1] + red[2][R][1] + red[3][R][1];
            float mu  = s * (1.0f / H);
            float var = q * (1.0f / H) - mu * mu;
            float rs  = rsqrtf(var + LN_EPS);
            #pragma unroll
            for (int f = 0; f < 4; ++f) {
                float o = (vv[f][r] - mu) * rs * g1v[f] + b1v[f];
                sfH[R][col[f]] = (_Float16)fmaxf(o, 0.f);
            }
        }
    }

    // ---- GEMM2: K = 256
    f32x4 acc2[4];
    #pragma unroll
    for (int f = 0; f < 4; ++f) acc2[f] = (f32x4)(0.f);

    for (int k0 = 0; k0 < H; k0 += KT) {
        {   // stage WfsH tile
            const int4* src = (const int4*)(WfsH + (size_t)k0 * H);
            int4* dst = (int4*)&sW[0][0];
            #pragma unroll
            for (int j = 0; j < 4; ++j) dst[t + j * 256] = src[t + j * 256];
        }
        __syncthreads();
        #pragma unroll
        for (int ks = 0; ks < 2; ++ks) {
            const int kb = ks * 16 + 4 * grp;
            half4v a = *(const half4v*)&sfH[li][k0 + kb];
            #pragma unroll
            for (int f = 0; f < 4; ++f) {
                half4v b;
                b[0] = sW[kb + 0][col[f]];
                b[1] = sW[kb + 1][col[f]];
                b[2] = sW[kb + 2][col[f]];
                b[3] = sW[kb + 3][col[f]];
                acc2[f] = __builtin_amdgcn_mfma_f32_16x16x16f16(a, b, acc2[f], 0, 0, 0);
            }
        }
        __syncthreads();
    }

    // ---- bias + LN2 + ReLU -> out
    {
        float bfv[4], g2v[4], b2v[4];
        #pragma unroll
        for (int f = 0; f < 4; ++f) { bfv[f] = bf[col[f]]; g2v[f] = g2[col[f]]; b2v[f] = b2[col[f]]; }

        float vv[4][4], sum[4] = {0,0,0,0}, sq[4] = {0,0,0,0};
        #pragma unroll
        for (int f = 0; f < 4; ++f)
            #pragma unroll
            for (int r = 0; r < 4; ++r) {
                float v = acc2[f][r] + bfv[f];
                vv[f][r] = v;
                sum[r] += v; sq[r] += v * v;
            }
        #pragma unroll
        for (int r = 0; r < 4; ++r) {
            #pragma unroll
            for (int off = 1; off < 16; off <<= 1) {
                sum[r] += __shfl_xor(sum[r], off, 64);
                sq[r]  += __shfl_xor(sq[r],  off, 64);
            }
        }
        if (li == 0) {
            #pragma unroll
            for (int r = 0; r < 4; ++r) {
                red[w][4 * grp + r][0] = sum[r];
                red[w][4 * grp + r][1] = sq[r];
            }
        }
        __syncthreads();
        #pragma unroll
        for (int r = 0; r < 4; ++r) {
            int R = 4 * grp + r;
            float s = red[0][R][0] + red[1][R][0] + red[2][R][0] + red[3][R][0];
            float q = red[0][R][1] + red[1][R][1] + red[2][R][1] + red[3][R][1];
            float mu  = s * (1.0f / H);
            float var = q * (1.0f / H) - mu * mu;
            float rs  = rsqrtf(var + LN_EPS);
            int g = g0 + R;
            if (g < G) {
                #pragma unroll
                for (int f = 0; f < 4; ++f) {
                    float o = (vv[f][r] - mu) * rs * g2v[f] + b2v[f];
                    out[(size_t)g * H + col[f]] = fmaxf(o, 0.f);
                }
            }
        }
    }
}

// ---------------- launch ----------------

extern "C" void kernel_launch(void* const* d_in, const int* in_sizes, int n_in,
                              void* d_out, int out_size, void* d_ws, size_t ws_size,
                              hipStream_t stream) {
    const float* x   = (const float*)d_in[0];
    const int*   fid = (const int*)d_in[2];
    const float* Wp  = (const float*)d_in[3];
    const float* bp  = (const float*)d_in[4];
    const float* g1  = (const float*)d_in[5];
    const float* b1  = (const float*)d_in[6];
    const float* Wf  = (const float*)d_in[7];
    const float* bf  = (const float*)d_in[8];
    const float* g2  = (const float*)d_in[9];
    const float* b2  = (const float*)d_in[10];
    float* out = (float*)d_out;

    const int N = in_sizes[1];              // 500000
    const int G = out_size / H;             // 8192
    const int Ga = (G + ROWS - 1) & ~(ROWS - 1);

    char* w = (char*)d_ws;
    int* counts  = (int*)w;  w += (size_t)G * sizeof(int);
    int* offsets = (int*)w;  w += (size_t)G * sizeof(int);
    int* rank    = (int*)w;  w += (size_t)N * sizeof(int);
    int* idx     = (int*)w;  w += (size_t)N * sizeof(int);
    w = (char*)(((uintptr_t)w + 15) & ~(uintptr_t)15);
    float* pooled = (float*)w;      w += (size_t)Ga * H2 * sizeof(float);
    _Float16* WpH  = (_Float16*)w;  w += (size_t)H2 * H * sizeof(_Float16);
    _Float16* WfsH = (_Float16*)w;  w += (size_t)H * H * sizeof(_Float16);

    hipLaunchKernelGGL(k_zero,      dim3((G + 255) / 256), dim3(256), 0, stream, counts, G);
    hipLaunchKernelGGL(k_hist_rank, dim3(1024), dim3(256), 0, stream, fid, counts, rank, N);
    hipLaunchKernelGGL(k_scan,      dim3(1), dim3(1024), 0, stream, counts, offsets, G);
    hipLaunchKernelGGL(k_scatter,   dim3(1024), dim3(256), 0, stream, fid, rank, offsets, idx, N);
    hipLaunchKernelGGL(k_prep,      dim3(256), dim3(256), 0, stream, Wp, Wf, WpH, WfsH);
    hipLaunchKernelGGL(k_reduce,    dim3((G + 3) / 4), dim3(256), 0, stream,
                       x, idx, offsets, counts, pooled, G);
    hipLaunchKernelGGL(k_mlp,       dim3(Ga / ROWS), dim3(256), 0, stream,
                       pooled, WpH, bp, g1, b1, WfsH, bf, g2, b2, out, G);
}